// Round 17
// baseline (88.055 us; speedup 1.0000x reference)
//
#include <hip/hip_runtime.h>
#include <stdint.h>

#define ALPHA 0.2f
#define LOG2E 1.44269504089f

typedef __attribute__((ext_vector_type(8))) short s16x8;
typedef __attribute__((ext_vector_type(4))) float f32x4;
typedef __attribute__((ext_vector_type(4))) unsigned u32x4;

__device__ __forceinline__ unsigned short f2bf(float f) {
    union { float f; unsigned u; } c; c.f = f;
    unsigned u = c.u;
    u += 0x7fffu + ((u >> 16) & 1u);
    return (unsigned short)(u >> 16);
}

// ---- prep: wT bf16 [c=256][f=256] (c=(h,e)) + wa1/wa2 = log2e * W@a{1,2} ----
__global__ void k_prep_w(const float* __restrict__ weight, const float* __restrict__ att,
                         unsigned short* __restrict__ wT, float* __restrict__ wa1,
                         float* __restrict__ wa2) {
    int blk = blockIdx.x, t = threadIdx.x;
    if (blk < 256) {
        int c = blk, h = c >> 5, e = c & 31;
        wT[c * 256 + t] = f2bf(weight[h * 8192 + t * 32 + e]);
    } else {
        int id = blk - 256, h = id >> 1, which = id & 1;
        float s = 0.f;
        for (int e = 0; e < 32; ++e)
            s += weight[h * 8192 + t * 32 + e] * att[h * 64 + which * 32 + e];
        s *= LOG2E;   // scores in log2 domain (leaky commutes with positive scale)
        (which ? wa2 : wa1)[h * 256 + t] = s;
    }
}

// ---- fused: adj->gmask ballots, x->LDS bf16, s1/s2 dots (x via L1), Wh^T MFMA ----
__global__ void __launch_bounds__(512) k_pre(const int* __restrict__ adj,
                                             unsigned* __restrict__ gmask,
                                             const float* __restrict__ x,
                                             const unsigned short* __restrict__ wT,
                                             const float* __restrict__ wa1,
                                             const float* __restrict__ wa2,
                                             float* __restrict__ s1,
                                             float* __restrict__ s2,
                                             unsigned short* __restrict__ WhT) {
    __shared__ unsigned char adjb[16][1024];   // 0/1 bytes, col ^ ((row&7)<<4) swizzle
    __shared__ unsigned short x16s[16][256];   // bf16 rows, 16B-unit XOR swizzle
    int blk = blockIdx.x;                      // blk = b*64 + mt
    int t = threadIdx.x, w = t >> 6, l = t & 63;
    int b = blk >> 6;
    const int* abase = adj + blk * 16384;
#pragma unroll
    for (int it = 0; it < 8; ++it) {
        int f = it * 512 + t;
        int4 v = *(const int4*)(abase + f * 4);
        int row = f >> 8, col = (f & 255) * 4;
        unsigned p1 = __builtin_amdgcn_perm((unsigned)v.y, (unsigned)v.x, 0x00000400u);
        unsigned p2 = __builtin_amdgcn_perm((unsigned)v.w, (unsigned)v.z, 0x00000400u);
        unsigned pk = __builtin_amdgcn_perm(p2, p1, 0x05040100u);
        *(unsigned*)&adjb[row][col ^ ((row & 7) << 4)] = pk;
    }
    const float* xbase = x + blk * 4096;
#pragma unroll
    for (int it = 0; it < 2; ++it) {
        int f = it * 512 + t;
        float4 xv = *(const float4*)(xbase + f * 4);
        int row = f >> 6, col = (f & 63) * 4;
        ushort4 hv;
        hv.x = f2bf(xv.x); hv.y = f2bf(xv.y); hv.z = f2bf(xv.z); hv.w = f2bf(xv.w);
        *(ushort4*)((char*)&x16s[0][0] + ((row * 512 + col * 2) ^ ((row & 7) << 4))) = hv;
    }
    __syncthreads();
    if (w < 4) {
        for (int k = 0; k < 64; ++k) {
            int task = w * 64 + k;
            int row = task >> 4, ch = task & 15;
            unsigned char byv = adjb[row][(ch * 64 + l) ^ ((row & 7) << 4)];
            unsigned long long mk = __ballot(byv != 0);
            if (l == 0) {
                unsigned* dst = gmask + (blk * 16 + row) * 32 + ch * 2;
                dst[0] = (unsigned)mk;
                dst[1] = (unsigned)(mk >> 32);
            }
        }
    } else {
        // s1/s2 dots read x from global (block slice is L1-resident, fp32-exact)
        int td = (w - 4) * 64 + l;
        int row = td & 15, grp = td >> 4;
        int h = grp >> 1, which = grp & 1;
        const float* wap = (which ? wa2 : wa1) + h * 256;
        const float* xrow = xbase + row * 256;
        float s = 0.f;
#pragma unroll 4
        for (int f = 0; f < 256; f += 4) {
            f32x4 xv = *(const f32x4*)&xrow[f];
            f32x4 wv = *(const f32x4*)&wap[f];
            s += xv[0] * wv[0] + xv[1] * wv[1] + xv[2] * wv[2] + xv[3] * wv[3];
        }
        int m = (blk & 63) * 16 + row;
        (which ? s2 : s1)[(b * 8 + h) * 1024 + m] = s;
    }
    int lrow = l & 15, lk = l >> 4;
#pragma unroll
    for (int ct = 0; ct < 2; ++ct) {
        int c0 = (w * 2 + ct) * 16;
        f32x4 acc = {0, 0, 0, 0};
        const unsigned short* ap = wT + (c0 + lrow) * 256 + lk * 8;
#pragma unroll
        for (int k0 = 0; k0 < 256; k0 += 32) {
            s16x8 af = *(const s16x8*)(ap + k0);
            s16x8 bf = *(const s16x8*)((char*)&x16s[0][0] +
                        ((lrow * 512 + (lk * 8 + k0) * 2) ^ ((lrow & 7) << 4)));
            acc = __builtin_amdgcn_mfma_f32_16x16x32_bf16(af, bf, acc, 0, 0, 0);
        }
#pragma unroll
        for (int j = 0; j < 4; ++j) {
            int c = c0 + lk * 4 + j;
            WhT[(b * 256 + c) * 1024 + (blk & 63) * 16 + lrow] = f2bf(acc[j]);
        }
    }
}

// ---- top-16 of s2 per (b,h): sorted desc values + indices ----
__global__ void __launch_bounds__(64) k_top(const float* __restrict__ s2,
                                            float* __restrict__ tval,
                                            unsigned* __restrict__ tidx) {
    int bh = blockIdx.x, l = threadIdx.x;
    const float* p = s2 + bh * 1024;
    float v[16];
#pragma unroll
    for (int k = 0; k < 4; ++k) {
        f32x4 x4 = *(const f32x4*)(p + l * 16 + k * 4);
        v[k * 4 + 0] = x4[0]; v[k * 4 + 1] = x4[1];
        v[k * 4 + 2] = x4[2]; v[k * 4 + 3] = x4[3];
    }
    unsigned used = 0;
    for (int r = 0; r < 16; ++r) {
        float lmax = -3.0e38f; int larg = 0;
#pragma unroll
        for (int k = 0; k < 16; ++k) {
            float c = ((used >> k) & 1u) ? -3.0e38f : v[k];
            if (c > lmax) { lmax = c; larg = k; }
        }
        float wmax = lmax;
#pragma unroll
        for (int off = 32; off >= 1; off >>= 1) wmax = fmaxf(wmax, __shfl_xor(wmax, off));
        unsigned long long hm = __ballot(lmax == wmax);
        int fl = (int)__builtin_ctzll(hm);
        if (l == fl) {
            tval[bh * 16 + r] = wmax;
            tidx[bh * 16 + r] = (unsigned)(l * 16 + larg);
            used |= 1u << larg;
        }
    }
}

// ---- attention: 2048 blocks x 256 thr (2 heads x 2 n-halves), ~17KB LDS ->
//      8+ blocks/CU; top-16-probe row max; select-before-exp pass B ----
__global__ void __launch_bounds__(256, 8) k_attn(const unsigned* __restrict__ gmask,
                                                 const float* __restrict__ s1,
                                                 const float* __restrict__ s2,
                                                 const float* __restrict__ tval,
                                                 const unsigned* __restrict__ tidx,
                                                 const unsigned short* __restrict__ WhT,
                                                 float* __restrict__ out) {
    __shared__ float s2s[2][1024];
    __shared__ unsigned amaskw[16][36];
    __shared__ float s1s[2][16];
    __shared__ float accsh[2][64][13];
    int bid = blockIdx.x;
    int o = (bid & 7) * 256 + (bid >> 3);   // XCD swizzle: each XCD owns one b
    int b = o >> 8, r = o & 255;
    int mt = r >> 2, m0 = mt * 16, hg = (r & 3) * 2;
    int t = threadIdx.x, w = t >> 6, l = t & 63;
    int hd = w & 1, nh = w >> 1;
    for (int i = t; i < 2048; i += 256)
        s2s[i >> 10][i & 1023] = s2[b * 8192 + (hg + (i >> 10)) * 1024 + (i & 1023)];
    for (int i = t; i < 512; i += 256)
        amaskw[i >> 5][i & 31] = gmask[(b * 1024 + m0) * 32 + i];
    if (t < 32) s1s[t >> 4][t & 15] = s1[b * 8192 + (hg + (t >> 4)) * 1024 + m0 + (t & 15)];
    __syncthreads();
    int m = l & 15, q = l >> 4;
    int h = hg + hd;
    int nbase = nh * 512;
    // ---- pass A': probe top-16 sorted ranks (exact w.h.p.; miss -> val[15]
    //      upper bound, still safe with select-before-exp) ----
    const float*    tv = tval + (b * 8 + h) * 16;
    const unsigned* ti = tidx + (b * 8 + h) * 16;
    float mxs2 = tv[15];
#pragma unroll
    for (int j = 0; j < 16; ++j) {
        unsigned id = ti[j];
        unsigned wd = amaskw[m][id >> 5];
        unsigned bit = (wd >> (id & 31u)) & 1u;
        mxs2 = fmaxf(mxs2, bit ? tv[j] : -3.0e38f);
    }
    float s1v = s1s[hd][m];
    float mxr = s1v + mxs2;
    float mx = fmaxf(mxr, ALPHA * mxr);   // >= leaky(any masked score): safe shift
    float cc1 = s1v - mx;
    float cc2 = fmaf(ALPHA, s1v, -mx);
    u32x4 mv0 = *(const u32x4*)&amaskw[m][nh * 16];
    u32x4 mv1 = *(const u32x4*)&amaskw[m][nh * 16 + 4];
    u32x4 mv2 = *(const u32x4*)&amaskw[m][nh * 16 + 8];
    u32x4 mv3 = *(const u32x4*)&amaskw[m][nh * 16 + 12];
    // ---- pass B: arg = bit ? leaky(score)-mx : -3e38 (select BEFORE exp) ----
    f32x4 acc0 = {0,0,0,0}, acc1 = {0,0,0,0}, accs = {0,0,0,0};
    s16x8 ones;
#pragma unroll
    for (int u = 0; u < 8; ++u) ones[u] = (short)0x3F80;   // bf16 1.0
    const unsigned short* bp0 = WhT + (b * 8 + h) * 32768 + m * 1024 + q * 8 + nbase;
    const unsigned short* bp1 = bp0 + 16 * 1024;
#pragma unroll
    for (int i = 0; i < 16; ++i) {
        int n0 = i * 32;
        unsigned word = (i < 4 ? mv0[i & 3] : i < 8 ? mv1[i & 3] : i < 12 ? mv2[i & 3]
                                                                          : mv3[i & 3]);
        unsigned wm8 = word >> (q * 8);
        int nn = nbase + n0 + q * 8;
        f32x4 svA = *(const f32x4*)&s2s[hd][nn];
        f32x4 svB = *(const f32x4*)&s2s[hd][nn + 4];
        float pv[8];
#pragma unroll
        for (int u = 0; u < 8; ++u) {
            float sv = (u < 4 ? svA[u] : svB[u - 4]);
            float arg = fmaxf(sv + cc1, fmaf(ALPHA, sv, cc2));   // leaky(score)-mx
            arg = ((wm8 >> u) & 1u) ? arg : -3.0e38f;            // select BEFORE exp
            pv[u] = __builtin_amdgcn_exp2f(arg);
        }
        u32x4 aw;
#pragma unroll
        for (int p = 0; p < 4; ++p) {
            union { float f; unsigned u; } lo, hi;
            lo.f = pv[2 * p]; hi.f = pv[2 * p + 1];
            aw[p] = __builtin_amdgcn_perm(hi.u, lo.u, 0x07060302u);  // trunc-pack 2xbf16
        }
        s16x8 af = __builtin_bit_cast(s16x8, aw);
        s16x8 bf0 = *(const s16x8*)(bp0 + n0);
        s16x8 bf1 = *(const s16x8*)(bp1 + n0);
        acc0 = __builtin_amdgcn_mfma_f32_16x16x32_bf16(af, bf0, acc0, 0, 0, 0);
        acc1 = __builtin_amdgcn_mfma_f32_16x16x32_bf16(af, bf1, acc1, 0, 0, 0);
        accs = __builtin_amdgcn_mfma_f32_16x16x32_bf16(af, ones, accs, 0, 0, 0);
    }
    if (nh == 1) {
#pragma unroll
        for (int j = 0; j < 4; ++j) {
            accsh[hd][l][j]     = acc0[j];
            accsh[hd][l][4 + j] = acc1[j];
            accsh[hd][l][8 + j] = accs[j];
        }
    }
    __syncthreads();
    if (nh == 0) {
#pragma unroll
        for (int j = 0; j < 4; ++j) {
            float a0 = acc0[j] + accsh[hd][l][j];      // identical mx both halves
            float a1 = acc1[j] + accsh[hd][l][4 + j];
            float as = accs[j] + accsh[hd][l][8 + j];
            float inv = 1.f / as;
            float v0 = a0 * inv;
            float v1 = a1 * inv;
            v0 = v0 > 0.f ? v0 : __expf(v0) - 1.f;
            v1 = v1 > 0.f ? v1 : __expf(v1) - 1.f;
            int mrow = q * 4 + j;
            float* op = &out[(b * 1024 + m0 + mrow) * 256 + h * 32];
            op[m] = v0;
            op[16 + m] = v1;
        }
    }
}

extern "C" void kernel_launch(void* const* d_in, const int* in_sizes, int n_in,
                              void* d_out, int out_size, void* d_ws, size_t ws_size,
                              hipStream_t stream) {
    const float* x      = (const float*)d_in[0];
    const int*   adj    = (const int*)d_in[1];
    const float* weight = (const float*)d_in[2];
    const float* att    = (const float*)d_in[3];

    char* ws = (char*)d_ws;
    unsigned short* wT  = (unsigned short*)(ws);             // 128K
    unsigned short* WhT = (unsigned short*)(ws + 131072);    // 4M
    float* s1  = (float*)(ws + 4325376);                     // 256K
    float* s2  = (float*)(ws + 4587520);                     // 256K
    float* wa1 = (float*)(ws + 4849664);                     // 8K
    float* wa2 = (float*)(ws + 4857856);                     // 8K
    unsigned* gmask = (unsigned*)(ws + 4866048);             // 1M
    float*    tval  = (float*)(ws + 5914624);                // 4K
    unsigned* tidx  = (unsigned*)(ws + 5918720);             // 4K
    float* out = (float*)d_out;

    k_prep_w<<<272, 256, 0, stream>>>(weight, att, wT, wa1, wa2);
    k_pre<<<512, 512, 0, stream>>>(adj, gmask, x, wT, wa1, wa2, s1, s2, WhT);
    k_top<<<64, 64, 0, stream>>>(s2, tval, tidx);
    k_attn<<<2048, 256, 0, stream>>>(gmask, s1, s2, tval, tidx, WhT, out);
}

// Round 18
// 70.372 us; speedup vs baseline: 1.2513x; 1.2513x over previous
//
#include <hip/hip_runtime.h>
#include <stdint.h>

#define ALPHA 0.2f
#define LOG2E 1.44269504089f

typedef __attribute__((ext_vector_type(8))) short s16x8;
typedef __attribute__((ext_vector_type(4))) float f32x4;
typedef __attribute__((ext_vector_type(4))) unsigned u32x4;

__device__ __forceinline__ unsigned short f2bf(float f) {
    union { float f; unsigned u; } c; c.f = f;
    unsigned u = c.u;
    u += 0x7fffu + ((u >> 16) & 1u);
    return (unsigned short)(u >> 16);
}

// ---- prep: wT bf16 [c=256][f=256] (c=(h,e)) + wa1/wa2 = log2e * W@a{1,2} ----
__global__ void k_prep_w(const float* __restrict__ weight, const float* __restrict__ att,
                         unsigned short* __restrict__ wT, float* __restrict__ wa1,
                         float* __restrict__ wa2) {
    int blk = blockIdx.x, t = threadIdx.x;
    if (blk < 256) {
        int c = blk, h = c >> 5, e = c & 31;
        wT[c * 256 + t] = f2bf(weight[h * 8192 + t * 32 + e]);
    } else {
        int id = blk - 256, h = id >> 1, which = id & 1;
        float s = 0.f;
        for (int e = 0; e < 32; ++e)
            s += weight[h * 8192 + t * 32 + e] * att[h * 64 + which * 32 + e];
        s *= LOG2E;   // scores in log2 domain (leaky commutes with positive scale)
        (which ? wa2 : wa1)[h * 256 + t] = s;
    }
}

// ---- fused (r15-proven): adj->gmask, x->LDS (fp32 + swizzled bf16),
//      s1/s2 dots, Wh^T MFMA ----
__global__ void __launch_bounds__(512) k_pre(const int* __restrict__ adj,
                                             unsigned* __restrict__ gmask,
                                             const float* __restrict__ x,
                                             const unsigned short* __restrict__ wT,
                                             const float* __restrict__ wa1,
                                             const float* __restrict__ wa2,
                                             float* __restrict__ s1,
                                             float* __restrict__ s2,
                                             unsigned short* __restrict__ WhT) {
    __shared__ unsigned char adjb[16][1024];   // 0/1 bytes, col ^ ((row&7)<<4) swizzle
    __shared__ float xs[16][260];
    __shared__ unsigned short x16s[16][256];   // bf16 rows, 16B-unit XOR swizzle
    int blk = blockIdx.x;                      // blk = b*64 + mt
    int t = threadIdx.x, w = t >> 6, l = t & 63;
    int b = blk >> 6;
    const int* abase = adj + blk * 16384;
#pragma unroll
    for (int it = 0; it < 8; ++it) {
        int f = it * 512 + t;
        int4 v = *(const int4*)(abase + f * 4);
        int row = f >> 8, col = (f & 255) * 4;
        unsigned p1 = __builtin_amdgcn_perm((unsigned)v.y, (unsigned)v.x, 0x00000400u);
        unsigned p2 = __builtin_amdgcn_perm((unsigned)v.w, (unsigned)v.z, 0x00000400u);
        unsigned pk = __builtin_amdgcn_perm(p2, p1, 0x05040100u);
        *(unsigned*)&adjb[row][col ^ ((row & 7) << 4)] = pk;
    }
    const float* xbase = x + blk * 4096;
#pragma unroll
    for (int it = 0; it < 2; ++it) {
        int f = it * 512 + t;
        float4 xv = *(const float4*)(xbase + f * 4);
        int row = f >> 6, col = (f & 63) * 4;
        *(float4*)&xs[row][col] = xv;
        ushort4 hv;
        hv.x = f2bf(xv.x); hv.y = f2bf(xv.y); hv.z = f2bf(xv.z); hv.w = f2bf(xv.w);
        *(ushort4*)((char*)&x16s[0][0] + ((row * 512 + col * 2) ^ ((row & 7) << 4))) = hv;
    }
    __syncthreads();
    if (w < 4) {
        for (int k = 0; k < 64; ++k) {
            int task = w * 64 + k;
            int row = task >> 4, ch = task & 15;
            unsigned char byv = adjb[row][(ch * 64 + l) ^ ((row & 7) << 4)];
            unsigned long long mk = __ballot(byv != 0);
            if (l == 0) {
                unsigned* dst = gmask + (blk * 16 + row) * 32 + ch * 2;
                dst[0] = (unsigned)mk;
                dst[1] = (unsigned)(mk >> 32);
            }
        }
    } else {
        int td = (w - 4) * 64 + l;
        int row = td & 15, grp = td >> 4;
        int h = grp >> 1, which = grp & 1;
        const float* wap = (which ? wa2 : wa1) + h * 256;
        float s = 0.f;
#pragma unroll 4
        for (int f = 0; f < 256; f += 4) {
            f32x4 xv = *(const f32x4*)&xs[row][f];
            f32x4 wv = *(const f32x4*)&wap[f];
            s += xv[0] * wv[0] + xv[1] * wv[1] + xv[2] * wv[2] + xv[3] * wv[3];
        }
        int m = (blk & 63) * 16 + row;
        (which ? s2 : s1)[(b * 8 + h) * 1024 + m] = s;
    }
    int lrow = l & 15, lk = l >> 4;
#pragma unroll
    for (int ct = 0; ct < 2; ++ct) {
        int c0 = (w * 2 + ct) * 16;
        f32x4 acc = {0, 0, 0, 0};
        const unsigned short* ap = wT + (c0 + lrow) * 256 + lk * 8;
#pragma unroll
        for (int k0 = 0; k0 < 256; k0 += 32) {
            s16x8 af = *(const s16x8*)(ap + k0);
            s16x8 bf = *(const s16x8*)((char*)&x16s[0][0] +
                        ((lrow * 512 + (lk * 8 + k0) * 2) ^ ((lrow & 7) << 4)));
            acc = __builtin_amdgcn_mfma_f32_16x16x32_bf16(af, bf, acc, 0, 0, 0);
        }
#pragma unroll
        for (int j = 0; j < 4; ++j) {
            int c = c0 + lk * 4 + j;
            WhT[(b * 256 + c) * 1024 + (blk & 63) * 16 + lrow] = f2bf(acc[j]);
        }
    }
}

// ---- attention: r15 geometry + DUAL-CHAIN ILP (tiles 2i/2i+1 in disjoint
//      registers, split accumulators) ----
__global__ void __launch_bounds__(512, 4) k_attn(const unsigned* __restrict__ gmask,
                                                 const float* __restrict__ s1,
                                                 const float* __restrict__ s2,
                                                 const unsigned short* __restrict__ WhT,
                                                 float* __restrict__ out) {
    __shared__ float s2s[4][1024];
    __shared__ unsigned amaskw[16][36];
    __shared__ float s1s[4][16];
    __shared__ float mxsh[4][16][2];
    __shared__ float accsh[4][64][13];
    int bid = blockIdx.x;
    int o = (bid & 7) * 128 + (bid >> 3);   // XCD swizzle: each XCD owns one b
    int b = o >> 7, r = o & 127;
    int mt = r >> 1, m0 = mt * 16, hg = (r & 1) * 4;
    int t = threadIdx.x, w = t >> 6, l = t & 63;
    int hd = w & 3, nh = w >> 2;
    for (int i = t; i < 4096; i += 512)
        s2s[i >> 10][i & 1023] = s2[b * 8192 + hg * 1024 + i];
    amaskw[t >> 5][t & 31] = gmask[(b * 1024 + m0) * 32 + t];
    if (t < 64) s1s[t >> 4][t & 15] = s1[b * 8192 + (hg + (t >> 4)) * 1024 + m0 + (t & 15)];
    __syncthreads();
    int m = l & 15, q = l >> 4;
    int h = hg + hd;
    int nbase = nh * 512;
    u32x4 mv0 = *(const u32x4*)&amaskw[m][nh * 16];
    u32x4 mv1 = *(const u32x4*)&amaskw[m][nh * 16 + 4];
    u32x4 mv2 = *(const u32x4*)&amaskw[m][nh * 16 + 8];
    u32x4 mv3 = *(const u32x4*)&amaskw[m][nh * 16 + 12];
    // ---- pass A: masked row-max; DUAL chains (even/odd tiles) ----
    float me0 = -3.0e38f, me1 = -3.0e38f, me2 = -3.0e38f, me3 = -3.0e38f;
    float mo0 = -3.0e38f, mo1 = -3.0e38f, mo2 = -3.0e38f, mo3 = -3.0e38f;
#pragma unroll
    for (int ii = 0; ii < 8; ++ii) {
        const int ia = 2 * ii, ib = 2 * ii + 1;
        unsigned worda = (ia < 4 ? mv0[ia & 3] : ia < 8 ? mv1[ia & 3]
                          : ia < 12 ? mv2[ia & 3] : mv3[ia & 3]);
        unsigned wordb = (ib < 4 ? mv0[ib & 3] : ib < 8 ? mv1[ib & 3]
                          : ib < 12 ? mv2[ib & 3] : mv3[ib & 3]);
        unsigned wa8 = worda >> (q * 8);
        unsigned wb8 = wordb >> (q * 8);
        int na = nbase + ia * 32 + q * 8;
        int nb2 = nbase + ib * 32 + q * 8;
        f32x4 aA = *(const f32x4*)&s2s[hd][na];
        f32x4 aB = *(const f32x4*)&s2s[hd][na + 4];
        f32x4 bA = *(const f32x4*)&s2s[hd][nb2];
        f32x4 bB = *(const f32x4*)&s2s[hd][nb2 + 4];
        me0 = fmaxf(me0, fmaxf((wa8 & 1u)  ? aA[0] : -3.0e38f,
                               (wa8 & 2u)  ? aA[1] : -3.0e38f));
        me1 = fmaxf(me1, fmaxf((wa8 & 4u)  ? aA[2] : -3.0e38f,
                               (wa8 & 8u)  ? aA[3] : -3.0e38f));
        me2 = fmaxf(me2, fmaxf((wa8 & 16u) ? aB[0] : -3.0e38f,
                               (wa8 & 32u) ? aB[1] : -3.0e38f));
        me3 = fmaxf(me3, fmaxf((wa8 & 64u) ? aB[2] : -3.0e38f,
                               (wa8 & 128u)? aB[3] : -3.0e38f));
        mo0 = fmaxf(mo0, fmaxf((wb8 & 1u)  ? bA[0] : -3.0e38f,
                               (wb8 & 2u)  ? bA[1] : -3.0e38f));
        mo1 = fmaxf(mo1, fmaxf((wb8 & 4u)  ? bA[2] : -3.0e38f,
                               (wb8 & 8u)  ? bA[3] : -3.0e38f));
        mo2 = fmaxf(mo2, fmaxf((wb8 & 16u) ? bB[0] : -3.0e38f,
                               (wb8 & 32u) ? bB[1] : -3.0e38f));
        mo3 = fmaxf(mo3, fmaxf((wb8 & 64u) ? bB[2] : -3.0e38f,
                               (wb8 & 128u)? bB[3] : -3.0e38f));
    }
    float mxs2 = fmaxf(fmaxf(fmaxf(me0, me1), fmaxf(me2, me3)),
                       fmaxf(fmaxf(mo0, mo1), fmaxf(mo2, mo3)));
    mxs2 = fmaxf(mxs2, __shfl_xor(mxs2, 16));
    mxs2 = fmaxf(mxs2, __shfl_xor(mxs2, 32));   // masked max over this half, row m
    if (l < 16) mxsh[hd][l][nh] = mxs2;
    __syncthreads();
    float mxf = fmaxf(mxsh[hd][m][0], mxsh[hd][m][1]);   // full-row masked max
    float s1v = s1s[hd][m];
    float mxr = s1v + mxf;
    float mx = fmaxf(mxr, ALPHA * mxr);   // = leaky(best masked score): exact shift
    float cc1 = s1v - mx;
    float cc2 = fmaf(ALPHA, s1v, -mx);
    // ---- pass B: DUAL chains with split accumulators (exact: same mx) ----
    f32x4 accA0 = {0,0,0,0}, accA1 = {0,0,0,0}, accAs = {0,0,0,0};
    f32x4 accB0 = {0,0,0,0}, accB1 = {0,0,0,0}, accBs = {0,0,0,0};
    s16x8 ones;
#pragma unroll
    for (int u = 0; u < 8; ++u) ones[u] = (short)0x3F80;   // bf16 1.0
    const unsigned short* bp0 = WhT + (b * 8 + h) * 32768 + m * 1024 + q * 8 + nbase;
    const unsigned short* bp1 = bp0 + 16 * 1024;
#pragma unroll
    for (int ii = 0; ii < 8; ++ii) {
        const int ia = 2 * ii, ib = 2 * ii + 1;
        unsigned worda = (ia < 4 ? mv0[ia & 3] : ia < 8 ? mv1[ia & 3]
                          : ia < 12 ? mv2[ia & 3] : mv3[ia & 3]);
        unsigned wordb = (ib < 4 ? mv0[ib & 3] : ib < 8 ? mv1[ib & 3]
                          : ib < 12 ? mv2[ib & 3] : mv3[ib & 3]);
        unsigned wa8 = worda >> (q * 8);
        unsigned wb8 = wordb >> (q * 8);
        int na = nbase + ia * 32 + q * 8;
        int nb2 = nbase + ib * 32 + q * 8;
        f32x4 aA = *(const f32x4*)&s2s[hd][na];
        f32x4 aB = *(const f32x4*)&s2s[hd][na + 4];
        f32x4 bA = *(const f32x4*)&s2s[hd][nb2];
        f32x4 bB = *(const f32x4*)&s2s[hd][nb2 + 4];
        s16x8 bf0a = *(const s16x8*)(bp0 + ia * 32);
        s16x8 bf1a = *(const s16x8*)(bp1 + ia * 32);
        s16x8 bf0b = *(const s16x8*)(bp0 + ib * 32);
        s16x8 bf1b = *(const s16x8*)(bp1 + ib * 32);
        float pva[8], pvb[8];
#pragma unroll
        for (int u = 0; u < 8; ++u) {
            float sva = (u < 4 ? aA[u] : aB[u - 4]);
            float arga = fmaxf(sva + cc1, fmaf(ALPHA, sva, cc2));
            arga = ((wa8 >> u) & 1u) ? arga : -3.0e38f;
            pva[u] = __builtin_amdgcn_exp2f(arga);
            float svb = (u < 4 ? bA[u] : bB[u - 4]);
            float argb = fmaxf(svb + cc1, fmaf(ALPHA, svb, cc2));
            argb = ((wb8 >> u) & 1u) ? argb : -3.0e38f;
            pvb[u] = __builtin_amdgcn_exp2f(argb);
        }
        u32x4 awa, awb;
#pragma unroll
        for (int p = 0; p < 4; ++p) {
            union { float f; unsigned u; } lo, hi;
            lo.f = pva[2 * p]; hi.f = pva[2 * p + 1];
            awa[p] = __builtin_amdgcn_perm(hi.u, lo.u, 0x07060302u);
            lo.f = pvb[2 * p]; hi.f = pvb[2 * p + 1];
            awb[p] = __builtin_amdgcn_perm(hi.u, lo.u, 0x07060302u);
        }
        s16x8 afa = __builtin_bit_cast(s16x8, awa);
        s16x8 afb = __builtin_bit_cast(s16x8, awb);
        accA0 = __builtin_amdgcn_mfma_f32_16x16x32_bf16(afa, bf0a, accA0, 0, 0, 0);
        accB0 = __builtin_amdgcn_mfma_f32_16x16x32_bf16(afb, bf0b, accB0, 0, 0, 0);
        accA1 = __builtin_amdgcn_mfma_f32_16x16x32_bf16(afa, bf1a, accA1, 0, 0, 0);
        accB1 = __builtin_amdgcn_mfma_f32_16x16x32_bf16(afb, bf1b, accB1, 0, 0, 0);
        accAs = __builtin_amdgcn_mfma_f32_16x16x32_bf16(afa, ones, accAs, 0, 0, 0);
        accBs = __builtin_amdgcn_mfma_f32_16x16x32_bf16(afb, ones, accBs, 0, 0, 0);
    }
    f32x4 acc0, acc1, accs;
#pragma unroll
    for (int j = 0; j < 4; ++j) {
        acc0[j] = accA0[j] + accB0[j];
        acc1[j] = accA1[j] + accB1[j];
        accs[j] = accAs[j] + accBs[j];
    }
    if (nh == 1) {
#pragma unroll
        for (int j = 0; j < 4; ++j) {
            accsh[hd][l][j]     = acc0[j];
            accsh[hd][l][4 + j] = acc1[j];
            accsh[hd][l][8 + j] = accs[j];
        }
    }
    __syncthreads();
    if (nh == 0) {
#pragma unroll
        for (int j = 0; j < 4; ++j) {
            float a0 = acc0[j] + accsh[hd][l][j];
            float a1 = acc1[j] + accsh[hd][l][4 + j];
            float as = accs[j] + accsh[hd][l][8 + j];
            float inv = 1.f / as;
            float v0 = a0 * inv;
            float v1 = a1 * inv;
            v0 = v0 > 0.f ? v0 : __expf(v0) - 1.f;
            v1 = v1 > 0.f ? v1 : __expf(v1) - 1.f;
            int mrow = q * 4 + j;
            float* op = &out[(b * 1024 + m0 + mrow) * 256 + h * 32];
            op[m] = v0;
            op[16 + m] = v1;
        }
    }
}

extern "C" void kernel_launch(void* const* d_in, const int* in_sizes, int n_in,
                              void* d_out, int out_size, void* d_ws, size_t ws_size,
                              hipStream_t stream) {
    const float* x      = (const float*)d_in[0];
    const int*   adj    = (const int*)d_in[1];
    const float* weight = (const float*)d_in[2];
    const float* att    = (const float*)d_in[3];

    char* ws = (char*)d_ws;
    unsigned short* wT  = (unsigned short*)(ws);             // 128K
    unsigned short* WhT = (unsigned short*)(ws + 131072);    // 4M
    float* s1  = (float*)(ws + 4325376);                     // 256K
    float* s2  = (float*)(ws + 4587520);                     // 256K
    float* wa1 = (float*)(ws + 4849664);                     // 8K
    float* wa2 = (float*)(ws + 4857856);                     // 8K
    unsigned* gmask = (unsigned*)(ws + 4866048);             // 1M (end ~5.9MB)
    float* out = (float*)d_out;

    k_prep_w<<<272, 256, 0, stream>>>(weight, att, wT, wa1, wa2);
    k_pre<<<512, 512, 0, stream>>>(adj, gmask, x, wT, wa1, wa2, s1, s2, WhT);
    k_attn<<<1024, 512, 0, stream>>>(gmask, s1, s2, WhT, out);
}

// Round 19
// 63.357 us; speedup vs baseline: 1.3898x; 1.1107x over previous
//
#include <hip/hip_runtime.h>
#include <stdint.h>

#define ALPHA 0.2f
#define LOG2E 1.44269504089f
#define SKIP_THR 24.0f

typedef __attribute__((ext_vector_type(8))) short s16x8;
typedef __attribute__((ext_vector_type(4))) float f32x4;
typedef __attribute__((ext_vector_type(4))) unsigned u32x4;

__device__ __forceinline__ unsigned short f2bf(float f) {
    union { float f; unsigned u; } c; c.f = f;
    unsigned u = c.u;
    u += 0x7fffu + ((u >> 16) & 1u);
    return (unsigned short)(u >> 16);
}

// ---- prep: wT bf16 [c=256][f=256] (c=(h,e)) + wa1/wa2 = log2e * W@a{1,2} ----
__global__ void k_prep_w(const float* __restrict__ weight, const float* __restrict__ att,
                         unsigned short* __restrict__ wT, float* __restrict__ wa1,
                         float* __restrict__ wa2) {
    int blk = blockIdx.x, t = threadIdx.x;
    if (blk < 256) {
        int c = blk, h = c >> 5, e = c & 31;
        wT[c * 256 + t] = f2bf(weight[h * 8192 + t * 32 + e]);
    } else {
        int id = blk - 256, h = id >> 1, which = id & 1;
        float s = 0.f;
        for (int e = 0; e < 32; ++e)
            s += weight[h * 8192 + t * 32 + e] * att[h * 64 + which * 32 + e];
        s *= LOG2E;   // scores in log2 domain (leaky commutes with positive scale)
        (which ? wa2 : wa1)[h * 256 + t] = s;
    }
}

// ---- fused (r15-proven): adj->gmask, x->LDS (fp32 + swizzled bf16),
//      s1/s2 dots, Wh^T MFMA ----
__global__ void __launch_bounds__(512) k_pre(const int* __restrict__ adj,
                                             unsigned* __restrict__ gmask,
                                             const float* __restrict__ x,
                                             const unsigned short* __restrict__ wT,
                                             const float* __restrict__ wa1,
                                             const float* __restrict__ wa2,
                                             float* __restrict__ s1,
                                             float* __restrict__ s2,
                                             unsigned short* __restrict__ WhT) {
    __shared__ unsigned char adjb[16][1024];   // 0/1 bytes, col ^ ((row&7)<<4) swizzle
    __shared__ float xs[16][260];
    __shared__ unsigned short x16s[16][256];   // bf16 rows, 16B-unit XOR swizzle
    int blk = blockIdx.x;                      // blk = b*64 + mt
    int t = threadIdx.x, w = t >> 6, l = t & 63;
    int b = blk >> 6;
    const int* abase = adj + blk * 16384;
#pragma unroll
    for (int it = 0; it < 8; ++it) {
        int f = it * 512 + t;
        int4 v = *(const int4*)(abase + f * 4);
        int row = f >> 8, col = (f & 255) * 4;
        unsigned p1 = __builtin_amdgcn_perm((unsigned)v.y, (unsigned)v.x, 0x00000400u);
        unsigned p2 = __builtin_amdgcn_perm((unsigned)v.w, (unsigned)v.z, 0x00000400u);
        unsigned pk = __builtin_amdgcn_perm(p2, p1, 0x05040100u);
        *(unsigned*)&adjb[row][col ^ ((row & 7) << 4)] = pk;
    }
    const float* xbase = x + blk * 4096;
#pragma unroll
    for (int it = 0; it < 2; ++it) {
        int f = it * 512 + t;
        float4 xv = *(const float4*)(xbase + f * 4);
        int row = f >> 6, col = (f & 63) * 4;
        *(float4*)&xs[row][col] = xv;
        ushort4 hv;
        hv.x = f2bf(xv.x); hv.y = f2bf(xv.y); hv.z = f2bf(xv.z); hv.w = f2bf(xv.w);
        *(ushort4*)((char*)&x16s[0][0] + ((row * 512 + col * 2) ^ ((row & 7) << 4))) = hv;
    }
    __syncthreads();
    if (w < 4) {
        for (int k = 0; k < 64; ++k) {
            int task = w * 64 + k;
            int row = task >> 4, ch = task & 15;
            unsigned char byv = adjb[row][(ch * 64 + l) ^ ((row & 7) << 4)];
            unsigned long long mk = __ballot(byv != 0);
            if (l == 0) {
                unsigned* dst = gmask + (blk * 16 + row) * 32 + ch * 2;
                dst[0] = (unsigned)mk;
                dst[1] = (unsigned)(mk >> 32);
            }
        }
    } else {
        int td = (w - 4) * 64 + l;
        int row = td & 15, grp = td >> 4;
        int h = grp >> 1, which = grp & 1;
        const float* wap = (which ? wa2 : wa1) + h * 256;
        float s = 0.f;
#pragma unroll 4
        for (int f = 0; f < 256; f += 4) {
            f32x4 xv = *(const f32x4*)&xs[row][f];
            f32x4 wv = *(const f32x4*)&wap[f];
            s += xv[0] * wv[0] + xv[1] * wv[1] + xv[2] * wv[2] + xv[3] * wv[3];
        }
        int m = (blk & 63) * 16 + row;
        (which ? s2 : s1)[(b * 8 + h) * 1024 + m] = s;
    }
    int lrow = l & 15, lk = l >> 4;
#pragma unroll
    for (int ct = 0; ct < 2; ++ct) {
        int c0 = (w * 2 + ct) * 16;
        f32x4 acc = {0, 0, 0, 0};
        const unsigned short* ap = wT + (c0 + lrow) * 256 + lk * 8;
#pragma unroll
        for (int k0 = 0; k0 < 256; k0 += 32) {
            s16x8 af = *(const s16x8*)(ap + k0);
            s16x8 bf = *(const s16x8*)((char*)&x16s[0][0] +
                        ((lrow * 512 + (lk * 8 + k0) * 2) ^ ((lrow & 7) << 4)));
            acc = __builtin_amdgcn_mfma_f32_16x16x32_bf16(af, bf, acc, 0, 0, 0);
        }
#pragma unroll
        for (int j = 0; j < 4; ++j) {
            int c = c0 + lk * 4 + j;
            WhT[(b * 256 + c) * 1024 + (blk & 63) * 16 + lrow] = f2bf(acc[j]);
        }
    }
}

// ---- top-16 of s2 per (b,h): sorted desc values + indices (r16-proven) ----
__global__ void __launch_bounds__(64) k_top(const float* __restrict__ s2,
                                            float* __restrict__ tval,
                                            unsigned* __restrict__ tidx) {
    int bh = blockIdx.x, l = threadIdx.x;
    const float* p = s2 + bh * 1024;
    float v[16];
#pragma unroll
    for (int k = 0; k < 4; ++k) {
        f32x4 x4 = *(const f32x4*)(p + l * 16 + k * 4);
        v[k * 4 + 0] = x4[0]; v[k * 4 + 1] = x4[1];
        v[k * 4 + 2] = x4[2]; v[k * 4 + 3] = x4[3];
    }
    unsigned used = 0;
    for (int r = 0; r < 16; ++r) {
        float lmax = -3.0e38f; int larg = 0;
#pragma unroll
        for (int k = 0; k < 16; ++k) {
            float c = ((used >> k) & 1u) ? -3.0e38f : v[k];
            if (c > lmax) { lmax = c; larg = k; }
        }
        float wmax = lmax;
#pragma unroll
        for (int off = 32; off >= 1; off >>= 1) wmax = fmaxf(wmax, __shfl_xor(wmax, off));
        unsigned long long hm = __ballot(lmax == wmax);
        int fl = (int)__builtin_ctzll(hm);
        if (l == fl) {
            tval[bh * 16 + r] = wmax;
            tidx[bh * 16 + r] = (unsigned)(l * 16 + larg);
            used |= 1u << larg;
        }
    }
}

// ---- attention: r16 geometry + top-16-probe mx + TILE-SKIP
//      (skip 32-col tile when leaky(s1v+tmax32)-mx < -24 for all 16 rows:
//       contribution <= 32*2^-24, rsum >= 2^-10 -> rel err <= 2^-9) ----
__global__ void __launch_bounds__(256, 8) k_attn(const unsigned* __restrict__ gmask,
                                                 const float* __restrict__ s1,
                                                 const float* __restrict__ s2,
                                                 const float* __restrict__ tval,
                                                 const unsigned* __restrict__ tidx,
                                                 const unsigned short* __restrict__ WhT,
                                                 float* __restrict__ out) {
    __shared__ float s2s[2][1024];
    __shared__ unsigned amaskw[16][36];
    __shared__ float s1s[2][16];
    __shared__ float ptmx[2][32][4];
    __shared__ float tmx[2][32];
    __shared__ float accsh[2][64][13];
    int bid = blockIdx.x;
    int o = (bid & 7) * 256 + (bid >> 3);   // XCD swizzle: each XCD owns one b
    int b = o >> 8, r = o & 255;
    int mt = r >> 2, m0 = mt * 16, hg = (r & 3) * 2;
    int t = threadIdx.x, w = t >> 6, l = t & 63;
    int hd = w & 1, nh = w >> 1;
    for (int i = t; i < 2048; i += 256)
        s2s[i >> 10][i & 1023] = s2[b * 8192 + (hg + (i >> 10)) * 1024 + (i & 1023)];
    for (int i = t; i < 512; i += 256)
        amaskw[i >> 5][i & 31] = gmask[(b * 1024 + m0) * 32 + i];
    if (t < 32) s1s[t >> 4][t & 15] = s1[b * 8192 + (hg + (t >> 4)) * 1024 + m0 + (t & 15)];
    // per-tile s2 max partials straight from global (L2-warm; no LDS dep)
    {
        int hd2 = t >> 7, rem = t & 127, tile = rem >> 2, part = rem & 3;
        const float* sp = s2 + b * 8192 + (hg + hd2) * 1024 + tile * 32 + part * 8;
        f32x4 a = *(const f32x4*)sp;
        f32x4 c = *(const f32x4*)(sp + 4);
        ptmx[hd2][tile][part] = fmaxf(fmaxf(fmaxf(a[0], a[1]), fmaxf(a[2], a[3])),
                                      fmaxf(fmaxf(c[0], c[1]), fmaxf(c[2], c[3])));
    }
    __syncthreads();
    if (t < 64) {
        int hd2 = t >> 5, tile = t & 31;
        tmx[hd2][tile] = fmaxf(fmaxf(ptmx[hd2][tile][0], ptmx[hd2][tile][1]),
                               fmaxf(ptmx[hd2][tile][2], ptmx[hd2][tile][3]));
    }
    int m = l & 15, q = l >> 4;
    int h = hg + hd;
    int nbase = nh * 512;
    // ---- pass A': probe top-16 sorted ranks (exact w.h.p.; miss -> tv[15]
    //      upper bound within ~10 log2 of true; still safe) ----
    const float*    tv = tval + (b * 8 + h) * 16;
    const unsigned* ti = tidx + (b * 8 + h) * 16;
    float mxs2 = tv[15];
#pragma unroll
    for (int j = 0; j < 16; ++j) {
        unsigned id = ti[j];
        unsigned wd = amaskw[m][id >> 5];
        unsigned bit = (wd >> (id & 31u)) & 1u;
        mxs2 = fmaxf(mxs2, bit ? tv[j] : -3.0e38f);
    }
    float s1v = s1s[hd][m];
    float mxr = s1v + mxs2;
    float mx = fmaxf(mxr, ALPHA * mxr);   // >= leaky(any masked score): safe shift
    float cc1 = s1v - mx;
    float cc2 = fmaf(ALPHA, s1v, -mx);
    u32x4 mv0 = *(const u32x4*)&amaskw[m][nh * 16];
    u32x4 mv1 = *(const u32x4*)&amaskw[m][nh * 16 + 4];
    u32x4 mv2 = *(const u32x4*)&amaskw[m][nh * 16 + 8];
    u32x4 mv3 = *(const u32x4*)&amaskw[m][nh * 16 + 12];
    __syncthreads();   // tmx ready
    f32x4 tm0 = *(const f32x4*)&tmx[hd][nh * 16];
    f32x4 tm1 = *(const f32x4*)&tmx[hd][nh * 16 + 4];
    f32x4 tm2 = *(const f32x4*)&tmx[hd][nh * 16 + 8];
    f32x4 tm3 = *(const f32x4*)&tmx[hd][nh * 16 + 12];
    // ---- pass B with tile-skip ----
    f32x4 acc0 = {0,0,0,0}, acc1 = {0,0,0,0}, accs = {0,0,0,0};
    s16x8 ones;
#pragma unroll
    for (int u = 0; u < 8; ++u) ones[u] = (short)0x3F80;   // bf16 1.0
    const unsigned short* bp0 = WhT + (b * 8 + h) * 32768 + m * 1024 + q * 8 + nbase;
    const unsigned short* bp1 = bp0 + 16 * 1024;
#pragma unroll
    for (int i = 0; i < 16; ++i) {
        float tmf = (i < 4 ? tm0[i & 3] : i < 8 ? tm1[i & 3] : i < 12 ? tm2[i & 3]
                                                                      : tm3[i & 3]);
        // upper bound of this row's args in the tile (monotone leaky)
        float ub = fmaxf(tmf + cc1, fmaf(ALPHA, tmf, cc2));
        if (__any(ub >= -SKIP_THR)) {
            int n0 = i * 32;
            unsigned word = (i < 4 ? mv0[i & 3] : i < 8 ? mv1[i & 3]
                             : i < 12 ? mv2[i & 3] : mv3[i & 3]);
            unsigned wm8 = word >> (q * 8);
            int nn = nbase + n0 + q * 8;
            f32x4 svA = *(const f32x4*)&s2s[hd][nn];
            f32x4 svB = *(const f32x4*)&s2s[hd][nn + 4];
            float pv[8];
#pragma unroll
            for (int u = 0; u < 8; ++u) {
                float sv = (u < 4 ? svA[u] : svB[u - 4]);
                float arg = fmaxf(sv + cc1, fmaf(ALPHA, sv, cc2));   // leaky(score)-mx
                arg = ((wm8 >> u) & 1u) ? arg : -3.0e38f;            // select BEFORE exp
                pv[u] = __builtin_amdgcn_exp2f(arg);
            }
            u32x4 aw;
#pragma unroll
            for (int p = 0; p < 4; ++p) {
                union { float f; unsigned u; } lo, hi;
                lo.f = pv[2 * p]; hi.f = pv[2 * p + 1];
                aw[p] = __builtin_amdgcn_perm(hi.u, lo.u, 0x07060302u);  // pack 2xbf16
            }
            s16x8 af = __builtin_bit_cast(s16x8, aw);
            s16x8 bf0 = *(const s16x8*)(bp0 + n0);
            s16x8 bf1 = *(const s16x8*)(bp1 + n0);
            acc0 = __builtin_amdgcn_mfma_f32_16x16x32_bf16(af, bf0, acc0, 0, 0, 0);
            acc1 = __builtin_amdgcn_mfma_f32_16x16x32_bf16(af, bf1, acc1, 0, 0, 0);
            accs = __builtin_amdgcn_mfma_f32_16x16x32_bf16(af, ones, accs, 0, 0, 0);
        }
    }
    if (nh == 1) {
#pragma unroll
        for (int j = 0; j < 4; ++j) {
            accsh[hd][l][j]     = acc0[j];
            accsh[hd][l][4 + j] = acc1[j];
            accsh[hd][l][8 + j] = accs[j];
        }
    }
    __syncthreads();
    if (nh == 0) {
#pragma unroll
        for (int j = 0; j < 4; ++j) {
            float a0 = acc0[j] + accsh[hd][l][j];      // identical mx both halves
            float a1 = acc1[j] + accsh[hd][l][4 + j];
            float as = accs[j] + accsh[hd][l][8 + j];
            float inv = 1.f / as;
            float v0 = a0 * inv;
            float v1 = a1 * inv;
            v0 = v0 > 0.f ? v0 : __expf(v0) - 1.f;
            v1 = v1 > 0.f ? v1 : __expf(v1) - 1.f;
            int mrow = q * 4 + j;
            float* op = &out[(b * 1024 + m0 + mrow) * 256 + h * 32];
            op[m] = v0;
            op[16 + m] = v1;
        }
    }
}

extern "C" void kernel_launch(void* const* d_in, const int* in_sizes, int n_in,
                              void* d_out, int out_size, void* d_ws, size_t ws_size,
                              hipStream_t stream) {
    const float* x      = (const float*)d_in[0];
    const int*   adj    = (const int*)d_in[1];
    const float* weight = (const float*)d_in[2];
    const float* att    = (const float*)d_in[3];

    char* ws = (char*)d_ws;
    unsigned short* wT  = (unsigned short*)(ws);             // 128K
    unsigned short* WhT = (unsigned short*)(ws + 131072);    // 4M
    float* s1  = (float*)(ws + 4325376);                     // 256K
    float* s2  = (float*)(ws + 4587520);                     // 256K
    float* wa1 = (float*)(ws + 4849664);                     // 8K
    float* wa2 = (float*)(ws + 4857856);                     // 8K
    unsigned* gmask = (unsigned*)(ws + 4866048);             // 1M
    float*    tval  = (float*)(ws + 5914624);                // 4K
    unsigned* tidx  = (unsigned*)(ws + 5918720);             // 4K
    float* out = (float*)d_out;

    k_prep_w<<<272, 256, 0, stream>>>(weight, att, wT, wa1, wa2);
    k_pre<<<512, 512, 0, stream>>>(adj, gmask, x, wT, wa1, wa2, s1, s2, WhT);
    k_top<<<64, 64, 0, stream>>>(s2, tval, tidx);
    k_attn<<<2048, 256, 0, stream>>>(gmask, s1, s2, tval, tidx, WhT, out);
}

// Round 20
// 63.295 us; speedup vs baseline: 1.3912x; 1.0010x over previous
//
#include <hip/hip_runtime.h>
#include <stdint.h>

#define ALPHA 0.2f
#define LOG2E 1.44269504089f
#define SKIP_THR 24.0f

typedef __attribute__((ext_vector_type(8))) short s16x8;
typedef __attribute__((ext_vector_type(4))) float f32x4;
typedef __attribute__((ext_vector_type(4))) unsigned u32x4;

__device__ __forceinline__ unsigned short f2bf(float f) {
    union { float f; unsigned u; } c; c.f = f;
    unsigned u = c.u;
    u += 0x7fffu + ((u >> 16) & 1u);
    return (unsigned short)(u >> 16);
}

// ---- prep: wT bf16 [c=256][f=256] (c=(h,e)) + wa1/wa2 = log2e * W@a{1,2} ----
__global__ void k_prep_w(const float* __restrict__ weight, const float* __restrict__ att,
                         unsigned short* __restrict__ wT, float* __restrict__ wa1,
                         float* __restrict__ wa2) {
    int blk = blockIdx.x, t = threadIdx.x;
    if (blk < 256) {
        int c = blk, h = c >> 5, e = c & 31;
        wT[c * 256 + t] = f2bf(weight[h * 8192 + t * 32 + e]);
    } else {
        int id = blk - 256, h = id >> 1, which = id & 1;
        float s = 0.f;
        for (int e = 0; e < 32; ++e)
            s += weight[h * 8192 + t * 32 + e] * att[h * 64 + which * 32 + e];
        s *= LOG2E;   // scores in log2 domain (leaky commutes with positive scale)
        (which ? wa2 : wa1)[h * 256 + t] = s;
    }
}

// ---- fused (r15-proven): adj->gmask, x->LDS (fp32 + swizzled bf16),
//      s1/s2 dots, Wh^T MFMA ----
__global__ void __launch_bounds__(512) k_pre(const int* __restrict__ adj,
                                             unsigned* __restrict__ gmask,
                                             const float* __restrict__ x,
                                             const unsigned short* __restrict__ wT,
                                             const float* __restrict__ wa1,
                                             const float* __restrict__ wa2,
                                             float* __restrict__ s1,
                                             float* __restrict__ s2,
                                             unsigned short* __restrict__ WhT) {
    __shared__ unsigned char adjb[16][1024];   // 0/1 bytes, col ^ ((row&7)<<4) swizzle
    __shared__ float xs[16][260];
    __shared__ unsigned short x16s[16][256];   // bf16 rows, 16B-unit XOR swizzle
    int blk = blockIdx.x;                      // blk = b*64 + mt
    int t = threadIdx.x, w = t >> 6, l = t & 63;
    int b = blk >> 6;
    const int* abase = adj + blk * 16384;
#pragma unroll
    for (int it = 0; it < 8; ++it) {
        int f = it * 512 + t;
        int4 v = *(const int4*)(abase + f * 4);
        int row = f >> 8, col = (f & 255) * 4;
        unsigned p1 = __builtin_amdgcn_perm((unsigned)v.y, (unsigned)v.x, 0x00000400u);
        unsigned p2 = __builtin_amdgcn_perm((unsigned)v.w, (unsigned)v.z, 0x00000400u);
        unsigned pk = __builtin_amdgcn_perm(p2, p1, 0x05040100u);
        *(unsigned*)&adjb[row][col ^ ((row & 7) << 4)] = pk;
    }
    const float* xbase = x + blk * 4096;
#pragma unroll
    for (int it = 0; it < 2; ++it) {
        int f = it * 512 + t;
        float4 xv = *(const float4*)(xbase + f * 4);
        int row = f >> 6, col = (f & 63) * 4;
        *(float4*)&xs[row][col] = xv;
        ushort4 hv;
        hv.x = f2bf(xv.x); hv.y = f2bf(xv.y); hv.z = f2bf(xv.z); hv.w = f2bf(xv.w);
        *(ushort4*)((char*)&x16s[0][0] + ((row * 512 + col * 2) ^ ((row & 7) << 4))) = hv;
    }
    __syncthreads();
    if (w < 4) {
        for (int k = 0; k < 64; ++k) {
            int task = w * 64 + k;
            int row = task >> 4, ch = task & 15;
            unsigned char byv = adjb[row][(ch * 64 + l) ^ ((row & 7) << 4)];
            unsigned long long mk = __ballot(byv != 0);
            if (l == 0) {
                unsigned* dst = gmask + (blk * 16 + row) * 32 + ch * 2;
                dst[0] = (unsigned)mk;
                dst[1] = (unsigned)(mk >> 32);
            }
        }
    } else {
        int td = (w - 4) * 64 + l;
        int row = td & 15, grp = td >> 4;
        int h = grp >> 1, which = grp & 1;
        const float* wap = (which ? wa2 : wa1) + h * 256;
        float s = 0.f;
#pragma unroll 4
        for (int f = 0; f < 256; f += 4) {
            f32x4 xv = *(const f32x4*)&xs[row][f];
            f32x4 wv = *(const f32x4*)&wap[f];
            s += xv[0] * wv[0] + xv[1] * wv[1] + xv[2] * wv[2] + xv[3] * wv[3];
        }
        int m = (blk & 63) * 16 + row;
        (which ? s2 : s1)[(b * 8 + h) * 1024 + m] = s;
    }
    int lrow = l & 15, lk = l >> 4;
#pragma unroll
    for (int ct = 0; ct < 2; ++ct) {
        int c0 = (w * 2 + ct) * 16;
        f32x4 acc = {0, 0, 0, 0};
        const unsigned short* ap = wT + (c0 + lrow) * 256 + lk * 8;
#pragma unroll
        for (int k0 = 0; k0 < 256; k0 += 32) {
            s16x8 af = *(const s16x8*)(ap + k0);
            s16x8 bf = *(const s16x8*)((char*)&x16s[0][0] +
                        ((lrow * 512 + (lk * 8 + k0) * 2) ^ ((lrow & 7) << 4)));
            acc = __builtin_amdgcn_mfma_f32_16x16x32_bf16(af, bf, acc, 0, 0, 0);
        }
#pragma unroll
        for (int j = 0; j < 4; ++j) {
            int c = c0 + lk * 4 + j;
            WhT[(b * 256 + c) * 1024 + (blk & 63) * 16 + lrow] = f2bf(acc[j]);
        }
    }
}

// ---- top-16 of s2 per (b,h): sorted desc values + indices (r16-proven) ----
__global__ void __launch_bounds__(64) k_top(const float* __restrict__ s2,
                                            float* __restrict__ tval,
                                            unsigned* __restrict__ tidx) {
    int bh = blockIdx.x, l = threadIdx.x;
    const float* p = s2 + bh * 1024;
    float v[16];
#pragma unroll
    for (int k = 0; k < 4; ++k) {
        f32x4 x4 = *(const f32x4*)(p + l * 16 + k * 4);
        v[k * 4 + 0] = x4[0]; v[k * 4 + 1] = x4[1];
        v[k * 4 + 2] = x4[2]; v[k * 4 + 3] = x4[3];
    }
    unsigned used = 0;
    for (int r = 0; r < 16; ++r) {
        float lmax = -3.0e38f; int larg = 0;
#pragma unroll
        for (int k = 0; k < 16; ++k) {
            float c = ((used >> k) & 1u) ? -3.0e38f : v[k];
            if (c > lmax) { lmax = c; larg = k; }
        }
        float wmax = lmax;
#pragma unroll
        for (int off = 32; off >= 1; off >>= 1) wmax = fmaxf(wmax, __shfl_xor(wmax, off));
        unsigned long long hm = __ballot(lmax == wmax);
        int fl = (int)__builtin_ctzll(hm);
        if (l == fl) {
            tval[bh * 16 + r] = wmax;
            tidx[bh * 16 + r] = (unsigned)(l * 16 + larg);
            used |= 1u << larg;
        }
    }
}

// ---- attention v20: wave = FULL head-row (no n-split, no merge); s2/WhT from
//      global (L2-resident via XCD swizzle); top-16-probe mx; tile-skip ----
__global__ void __launch_bounds__(256, 4) k_attn(const unsigned* __restrict__ gmask,
                                                 const float* __restrict__ s1,
                                                 const float* __restrict__ s2,
                                                 const float* __restrict__ tval,
                                                 const unsigned* __restrict__ tidx,
                                                 const unsigned short* __restrict__ WhT,
                                                 float* __restrict__ out) {
    __shared__ unsigned amaskw[16][36];
    __shared__ float s1s[4][16];
    __shared__ float ptmx[4][32][4];
    __shared__ float tmx[4][32];
    int bid = blockIdx.x;
    int o = (bid & 7) * 128 + (bid >> 3);   // XCD swizzle: each XCD owns one b
    int b = o >> 7, r = o & 127;
    int mt = r >> 1, m0 = mt * 16, hg = (r & 1) * 4;
    int t = threadIdx.x, w = t >> 6, l = t & 63;
    for (int i = t; i < 512; i += 256)
        amaskw[i >> 5][i & 31] = gmask[(b * 1024 + m0) * 32 + i];
    if (t < 64) s1s[t >> 4][t & 15] = s1[b * 8192 + (hg + (t >> 4)) * 1024 + m0 + (t & 15)];
    // per-tile unmasked s2 maxes (from global; L2-warm)
#pragma unroll
    for (int it = 0; it < 2; ++it) {
        int task = it * 256 + t;
        int hd2 = task >> 7, rem = task & 127, tile = rem >> 2, part = rem & 3;
        const float* sp = s2 + b * 8192 + (hg + hd2) * 1024 + tile * 32 + part * 8;
        f32x4 a = *(const f32x4*)sp;
        f32x4 c = *(const f32x4*)(sp + 4);
        ptmx[hd2][tile][part] = fmaxf(fmaxf(fmaxf(a[0], a[1]), fmaxf(a[2], a[3])),
                                      fmaxf(fmaxf(c[0], c[1]), fmaxf(c[2], c[3])));
    }
    __syncthreads();
    if (t < 128) {
        int hd2 = t >> 5, tile = t & 31;
        tmx[hd2][tile] = fmaxf(fmaxf(ptmx[hd2][tile][0], ptmx[hd2][tile][1]),
                               fmaxf(ptmx[hd2][tile][2], ptmx[hd2][tile][3]));
    }
    __syncthreads();
    int m = l & 15, q = l >> 4;
    int h = hg + w;
    // tmx for this head into registers (broadcast LDS reads)
    f32x4 tm[8];
#pragma unroll
    for (int k = 0; k < 8; ++k) tm[k] = *(const f32x4*)&tmx[w][k * 4];
    // ---- pass A': probe top-16 sorted ranks (exact w.h.p.; miss -> tv[15]
    //      upper bound; safe with select-before-exp) ----
    const float*    tv = tval + (b * 8 + h) * 16;
    const unsigned* ti = tidx + (b * 8 + h) * 16;
    float mxs2 = tv[15];
#pragma unroll
    for (int j = 0; j < 16; ++j) {
        unsigned id = ti[j];
        unsigned wd = amaskw[m][id >> 5];
        unsigned bit = (wd >> (id & 31u)) & 1u;
        mxs2 = fmaxf(mxs2, bit ? tv[j] : -3.0e38f);
    }
    float s1v = s1s[w][m];
    float mxr = s1v + mxs2;
    float mx = fmaxf(mxr, ALPHA * mxr);   // >= leaky(any masked score): safe shift
    float cc1 = s1v - mx;
    float cc2 = fmaf(ALPHA, s1v, -mx);
    // ---- pass B: full row, tile-skip; s2/WhT straight from global ----
    f32x4 acc0 = {0,0,0,0}, acc1 = {0,0,0,0}, accs = {0,0,0,0};
    s16x8 ones;
#pragma unroll
    for (int u = 0; u < 8; ++u) ones[u] = (short)0x3F80;   // bf16 1.0
    const float* sgb = s2 + (b * 8 + h) * 1024 + q * 8;
    const unsigned short* bp0 = WhT + (b * 8 + h) * 32768 + m * 1024 + q * 8;
    const unsigned short* bp1 = bp0 + 16 * 1024;
#pragma unroll
    for (int i = 0; i < 32; ++i) {
        float tmf = tm[i >> 2][i & 3];
        float ub = fmaxf(tmf + cc1, fmaf(ALPHA, tmf, cc2));  // row's max arg in tile
        if (__any(ub >= -SKIP_THR)) {
            int n0 = i * 32;
            unsigned wm8 = amaskw[m][i] >> (q * 8);
            f32x4 svA = *(const f32x4*)(sgb + n0);
            f32x4 svB = *(const f32x4*)(sgb + n0 + 4);
            float pv[8];
#pragma unroll
            for (int u = 0; u < 8; ++u) {
                float sv = (u < 4 ? svA[u] : svB[u - 4]);
                float arg = fmaxf(sv + cc1, fmaf(ALPHA, sv, cc2));   // leaky-mx
                arg = ((wm8 >> u) & 1u) ? arg : -3.0e38f;            // select pre-exp
                pv[u] = __builtin_amdgcn_exp2f(arg);
            }
            u32x4 aw;
#pragma unroll
            for (int p = 0; p < 4; ++p) {
                union { float f; unsigned u; } lo, hi;
                lo.f = pv[2 * p]; hi.f = pv[2 * p + 1];
                aw[p] = __builtin_amdgcn_perm(hi.u, lo.u, 0x07060302u);  // 2xbf16 pack
            }
            s16x8 af = __builtin_bit_cast(s16x8, aw);
            s16x8 bf0 = *(const s16x8*)(bp0 + n0);
            s16x8 bf1 = *(const s16x8*)(bp1 + n0);
            acc0 = __builtin_amdgcn_mfma_f32_16x16x32_bf16(af, bf0, acc0, 0, 0, 0);
            acc1 = __builtin_amdgcn_mfma_f32_16x16x32_bf16(af, bf1, acc1, 0, 0, 0);
            accs = __builtin_amdgcn_mfma_f32_16x16x32_bf16(af, ones, accs, 0, 0, 0);
        }
    }
    // ---- epilogue: accs IS the row-sum (full row in this wave) ----
#pragma unroll
    for (int j = 0; j < 4; ++j) {
        float inv = 1.f / accs[j];
        float v0 = acc0[j] * inv;
        float v1 = acc1[j] * inv;
        v0 = v0 > 0.f ? v0 : __expf(v0) - 1.f;
        v1 = v1 > 0.f ? v1 : __expf(v1) - 1.f;
        int mrow = q * 4 + j;
        float* op = &out[(b * 1024 + m0 + mrow) * 256 + h * 32];
        op[m] = v0;
        op[16 + m] = v1;
    }
}

extern "C" void kernel_launch(void* const* d_in, const int* in_sizes, int n_in,
                              void* d_out, int out_size, void* d_ws, size_t ws_size,
                              hipStream_t stream) {
    const float* x      = (const float*)d_in[0];
    const int*   adj    = (const int*)d_in[1];
    const float* weight = (const float*)d_in[2];
    const float* att    = (const float*)d_in[3];

    char* ws = (char*)d_ws;
    unsigned short* wT  = (unsigned short*)(ws);             // 128K
    unsigned short* WhT = (unsigned short*)(ws + 131072);    // 4M
    float* s1  = (float*)(ws + 4325376);                     // 256K
    float* s2  = (float*)(ws + 4587520);                     // 256K
    float* wa1 = (float*)(ws + 4849664);                     // 8K
    float* wa2 = (float*)(ws + 4857856);                     // 8K
    unsigned* gmask = (unsigned*)(ws + 4866048);             // 1M
    float*    tval  = (float*)(ws + 5914624);                // 4K
    unsigned* tidx  = (unsigned*)(ws + 5918720);             // 4K
    float* out = (float*)d_out;

    k_prep_w<<<272, 256, 0, stream>>>(weight, att, wT, wa1, wa2);
    k_pre<<<512, 512, 0, stream>>>(adj, gmask, x, wT, wa1, wa2, s1, s2, WhT);
    k_top<<<64, 64, 0, stream>>>(s2, tval, tidx);
    k_attn<<<1024, 256, 0, stream>>>(gmask, s1, s2, tval, tidx, WhT, out);
}